// Round 1
// baseline (1159.173 us; speedup 1.0000x reference)
//
#include <hip/hip_runtime.h>
#include <cmath>

#define HH 256
#define NB 32
#define LSEQ 50
#define BB 512
#define VOC 100000

// ---------------- generic tiled fp32 GEMM: C[M,N] = A[M,K]@W[K,N] + bias[N]
// 64x64 tile, 256 threads, 4x4 per thread, K-step 16. All dims multiples of 64/16.
#define TS 64
#define KSTEP 16
#define LDP 68   // padded LDS row stride (floats); 68*4B = 272B keeps 16B alignment

__global__ __launch_bounds__(256) void gemm_nn_bias(
    const float* __restrict__ A, const float* __restrict__ W,
    const float* __restrict__ bias, float* __restrict__ C,
    int M, int N, int K)
{
  __shared__ float As[KSTEP * LDP];   // As[kk][m] = A[m0+m][k0+kk]
  __shared__ float Ws[KSTEP * LDP];   // Ws[kk][n] = W[k0+kk][n0+n]
  const int tid = threadIdx.x;
  const int tx = tid & 15, ty = tid >> 4;
  const int n0 = blockIdx.x * TS, m0 = blockIdx.y * TS;

  const int lkk = tid & 15, lm = tid >> 4;   // A loader: kk fast (coalesced 16-wide)
  const int ln  = tid & 63, lkr = tid >> 6;  // W loader: n fast (coalesced 64-wide)

  float acc[4][4] = {};

  for (int k0 = 0; k0 < K; k0 += KSTEP) {
#pragma unroll
    for (int r = 0; r < 4; ++r)
      As[lkk * LDP + lm + r * 16] = A[(m0 + lm + r * 16) * K + k0 + lkk];
#pragma unroll
    for (int r = 0; r < 4; ++r)
      Ws[(lkr + r * 4) * LDP + ln] = W[(k0 + lkr + r * 4) * N + n0 + ln];
    __syncthreads();
#pragma unroll
    for (int kk = 0; kk < KSTEP; ++kk) {
      const float4 a4 = *(const float4*)(As + kk * LDP + ty * 4);
      const float4 w4 = *(const float4*)(Ws + kk * LDP + tx * 4);
      const float av[4] = {a4.x, a4.y, a4.z, a4.w};
      const float wv[4] = {w4.x, w4.y, w4.z, w4.w};
#pragma unroll
      for (int i = 0; i < 4; ++i)
#pragma unroll
        for (int j = 0; j < 4; ++j)
          acc[i][j] += av[i] * wv[j];
    }
    __syncthreads();
  }

  const float4 b4 = *(const float4*)(bias + n0 + tx * 4);
  const float bv[4] = {b4.x, b4.y, b4.z, b4.w};
#pragma unroll
  for (int i = 0; i < 4; ++i) {
    float4 o;
    o.x = acc[i][0] + bv[0];
    o.y = acc[i][1] + bv[1];
    o.z = acc[i][2] + bv[2];
    o.w = acc[i][3] + bv[3];
    *(float4*)(C + (m0 + ty * 4 + i) * N + n0 + tx * 4) = o;
  }
}

// ---------------- scores = seq_emb[512,256] @ emb[1:][100000,256]^T  (NT GEMM)
__global__ __launch_bounds__(256) void gemm_nt_scores(
    const float* __restrict__ A,    // seq_emb [512,256]
    const float* __restrict__ emb,  // [(V+1),256]
    float* __restrict__ C)          // [512, V]
{
  __shared__ float As[KSTEP * LDP];  // As[kk][m]
  __shared__ float Bs[KSTEP * LDP];  // Bs[kk][v]
  const int tid = threadIdx.x;
  const int tx = tid & 15, ty = tid >> 4;
  const int m0 = blockIdx.x * TS;   // 8 tiles
  const int v0 = blockIdx.y * TS;   // 1563 tiles (last partial)

  const int lkk = tid & 15, lr = tid >> 4;
  float acc[4][4] = {};

  for (int k0 = 0; k0 < HH; k0 += KSTEP) {
#pragma unroll
    for (int s = 0; s < 4; ++s)
      As[lkk * LDP + lr + s * 16] = A[(m0 + lr + s * 16) * HH + k0 + lkk];
#pragma unroll
    for (int s = 0; s < 4; ++s) {
      const int v = v0 + lr + s * 16;
      Bs[lkk * LDP + lr + s * 16] = (v < VOC) ? emb[(v + 1) * HH + k0 + lkk] : 0.f;
    }
    __syncthreads();
#pragma unroll
    for (int kk = 0; kk < KSTEP; ++kk) {
      const float4 a4 = *(const float4*)(As + kk * LDP + ty * 4);
      const float4 b4 = *(const float4*)(Bs + kk * LDP + tx * 4);
      const float av[4] = {a4.x, a4.y, a4.z, a4.w};
      const float bv[4] = {b4.x, b4.y, b4.z, b4.w};
#pragma unroll
      for (int i = 0; i < 4; ++i)
#pragma unroll
        for (int j = 0; j < 4; ++j)
          acc[i][j] += av[i] * bv[j];
    }
    __syncthreads();
  }
#pragma unroll
  for (int i = 0; i < 4; ++i) {
    const int m = m0 + ty * 4 + i;
#pragma unroll
    for (int j = 0; j < 4; ++j) {
      const int v = v0 + tx * 4 + j;
      if (v < VOC) C[m * VOC + v] = acc[i][j];
    }
  }
}

// ---------------- h0[b,n,:] = emb[items[b,n],:]  (float4 granularity)
__global__ void gather_h0(const int* __restrict__ items, const float* __restrict__ emb,
                          float* __restrict__ h0, int total4)
{
  const int e = blockIdx.x * blockDim.x + threadIdx.x;
  if (e >= total4) return;
  const int row = e >> 6, c = e & 63;  // 64 float4 per row of 256
  const int it = items[row];
  ((float4*)h0)[e] = ((const float4*)emb)[it * 64 + c];
}

// ---------------- a_cat[b,i,0:256]=A_in[b]@hin[b], a_cat[b,i,256:512]=A_out[b]@hout[b]
__global__ __launch_bounds__(256) void msg_kernel(
    const float* __restrict__ A, const float* __restrict__ hin,
    const float* __restrict__ hout, float* __restrict__ acat)
{
  const int b = blockIdx.x;
  const int tid = threadIdx.x;  // = output column c in [0,256)
  __shared__ float Ash[NB * 64];  // A[b] 32x64 row-major
#pragma unroll
  for (int r = 0; r < 8; ++r)
    Ash[tid + r * 256] = A[b * (NB * 2 * NB) + tid + r * 256];
  float hi[NB], ho[NB];
  const float* hinb = hin + b * NB * HH + tid;
  const float* houtb = hout + b * NB * HH + tid;
#pragma unroll
  for (int j = 0; j < NB; ++j) {
    hi[j] = hinb[j * HH];
    ho[j] = houtb[j * HH];
  }
  __syncthreads();
  for (int i = 0; i < NB; ++i) {
    float si = 0.f, so = 0.f;
#pragma unroll
    for (int j = 0; j < NB; ++j) {
      si += Ash[i * 64 + j] * hi[j];
      so += Ash[i * 64 + 32 + j] * ho[j];
    }
    acat[b * (NB * 2 * HH) + i * (2 * HH) + tid] = si;
    acat[b * (NB * 2 * HH) + i * (2 * HH) + HH + tid] = so;
  }
}

// ---------------- GRU cell elementwise; h updated in place
__global__ void gru_kernel(const float* __restrict__ gi, const float* __restrict__ gh,
                           float* __restrict__ h, int total)
{
  const int idx = blockIdx.x * blockDim.x + threadIdx.x;
  if (idx >= total) return;
  const int row = idx >> 8, k = idx & 255;
  const float* gir = gi + row * 768;
  const float* ghr = gh + row * 768;
  const float ir = gir[k], iz = gir[k + 256], inn = gir[k + 512];
  const float hr = ghr[k], hz = ghr[k + 256], hn = ghr[k + 512];
  const float r = 1.f / (1.f + expf(-(ir + hr)));
  const float z = 1.f / (1.f + expf(-(iz + hz)));
  const float n = tanhf(inn + r * hn);
  const float h0v = h[idx];
  h[idx] = n + z * (h0v - n);
}

// ---------------- h_seqs[b,l,:] = h[b,seq_alias[b,l],:]; h_tail[b,:] = h_seqs[b,tail,:]
__global__ __launch_bounds__(256) void seq_gather(
    const int* __restrict__ seq_alias, const int* __restrict__ mask,
    const float* __restrict__ h, float* __restrict__ h_seqs, float* __restrict__ h_tail)
{
  const int b = blockIdx.x, tid = threadIdx.x;
  __shared__ int tail_sh;
  if (tid == 0) {
    int s = 0;
    for (int l = 0; l < LSEQ; ++l) s += mask[b * LSEQ + l];
    tail_sh = s - 1;
  }
  __syncthreads();
  const int tail = tail_sh;
  for (int l = 0; l < LSEQ; ++l) {
    const int al = seq_alias[b * LSEQ + l];
    const float v = h[(b * NB + al) * HH + tid];
    h_seqs[(b * LSEQ + l) * HH + tid] = v;
    if (l == tail) h_tail[b * HH + tid] = v;
  }
}

// ---------------- alpha[b,l] = sum_k sigmoid(q1+q2)*fc3; seq_emb = sum_l alpha*h_seqs*mask
__global__ __launch_bounds__(256) void attn_kernel(
    const float* __restrict__ q1, const float* __restrict__ q2,
    const float* __restrict__ fc3_w, const float* __restrict__ h_seqs,
    const int* __restrict__ mask, float* __restrict__ seq_emb)
{
  const int b = blockIdx.x, k = threadIdx.x;
  __shared__ float red[4];
  __shared__ float alpha_sh;
  const float q1k = q1[b * HH + k];
  const float w3 = fc3_w[k];
  float acc = 0.f;
  for (int l = 0; l < LSEQ; ++l) {
    const float q2v = q2[(b * LSEQ + l) * HH + k];
    float v = (1.f / (1.f + expf(-(q1k + q2v)))) * w3;
#pragma unroll
    for (int off = 32; off > 0; off >>= 1) v += __shfl_down(v, off, 64);
    if ((k & 63) == 0) red[k >> 6] = v;
    __syncthreads();
    if (k == 0) alpha_sh = red[0] + red[1] + red[2] + red[3];
    __syncthreads();
    const float alpha = alpha_sh;
    if (mask[b * LSEQ + l]) acc += alpha * h_seqs[(b * LSEQ + l) * HH + k];
  }
  seq_emb[b * HH + k] = acc;
}

extern "C" void kernel_launch(void* const* d_in, const int* in_sizes, int n_in,
                              void* d_out, int out_size, void* d_ws, size_t ws_size,
                              hipStream_t stream)
{
  const float* A      = (const float*)d_in[0];
  const int* items    = (const int*)d_in[1];
  const int* seq_al   = (const int*)d_in[2];
  const int* mask     = (const int*)d_in[3];
  const float* emb    = (const float*)d_in[4];
  const float* W_in   = (const float*)d_in[5];
  const float* b_in   = (const float*)d_in[6];
  const float* W_out  = (const float*)d_in[7];
  const float* b_out  = (const float*)d_in[8];
  const float* W_ih   = (const float*)d_in[9];
  const float* b_ih   = (const float*)d_in[10];
  const float* W_hh   = (const float*)d_in[11];
  const float* b_hh   = (const float*)d_in[12];
  const float* fc1_w  = (const float*)d_in[13];
  const float* fc1_b  = (const float*)d_in[14];
  const float* fc2_w  = (const float*)d_in[15];
  const float* fc2_b  = (const float*)d_in[16];
  const float* fc3_w  = (const float*)d_in[17];
  float* out = (float*)d_out;

  // ws: h0 (16.8MB) + small vectors; all big intermediates live inside d_out (205MB)
  float* ws = (float*)d_ws;
  float* h0      = ws;                 // 4,194,304
  float* q1      = ws + 4194304;       // 131,072
  float* h_tail  = ws + 4325376;       // 131,072
  float* seq_emb = ws + 4456448;       // 131,072

  float* gi     = out;                 // 12,582,912
  float* gh     = out + 12582912;      // 12,582,912
  float* a_cat  = out + 25165824;      //  8,388,608
  float* hin    = out + 33554432;      //  4,194,304
  float* hout   = out + 37748736;      //  4,194,304  (ends 41,943,040 <= 51,200,000)
  float* h_seqs = out + 12582912;      // reuse gh region post-GRU (6,553,600)
  float* q2     = out;                 // reuse gi region post-GRU (6,553,600)

  const int MR = BB * NB;  // 16384 rows

  // 1. h0 = emb[items]
  gather_h0<<<dim3((MR * 64 + 255) / 256), dim3(256), 0, stream>>>(items, emb, h0, MR * 64);

  // 2/3. hin = h0@W_in + b_in ; hout = h0@W_out + b_out
  gemm_nn_bias<<<dim3(HH / TS, MR / TS), dim3(256), 0, stream>>>(h0, W_in, b_in, hin, MR, HH, HH);
  gemm_nn_bias<<<dim3(HH / TS, MR / TS), dim3(256), 0, stream>>>(h0, W_out, b_out, hout, MR, HH, HH);

  // 4. a_cat = [A_in@hin, A_out@hout]
  msg_kernel<<<dim3(BB), dim3(256), 0, stream>>>(A, hin, hout, a_cat);

  // 5. gh = h0@W_hh + b_hh ; 6. gi = a_cat@W_ih + b_ih
  gemm_nn_bias<<<dim3(768 / TS, MR / TS), dim3(256), 0, stream>>>(h0, W_hh, b_hh, gh, MR, 768, HH);
  gemm_nn_bias<<<dim3(768 / TS, MR / TS), dim3(256), 0, stream>>>(a_cat, W_ih, b_ih, gi, MR, 768, 2 * HH);

  // 7. GRU -> h (in place over h0)
  gru_kernel<<<dim3((MR * HH + 255) / 256), dim3(256), 0, stream>>>(gi, gh, h0, MR * HH);

  // 8. gather session sequences + tail
  seq_gather<<<dim3(BB), dim3(256), 0, stream>>>(seq_al, mask, h0, h_seqs, h_tail);

  // 9/10. q2 = h_seqs@fc2 + b ; q1 = h_tail@fc1 + b
  gemm_nn_bias<<<dim3(HH / TS, (BB * LSEQ) / TS), dim3(256), 0, stream>>>(h_seqs, fc2_w, fc2_b, q2, BB * LSEQ, HH, HH);
  gemm_nn_bias<<<dim3(HH / TS, BB / TS), dim3(256), 0, stream>>>(h_tail, fc1_w, fc1_b, q1, BB, HH, HH);

  // 11. attention pooling -> seq_emb
  attn_kernel<<<dim3(BB), dim3(256), 0, stream>>>(q1, q2, fc3_w, h_seqs, mask, seq_emb);

  // 12. scores = seq_emb @ emb[1:]^T  (overwrites all of d_out)
  gemm_nt_scores<<<dim3(BB / TS, (VOC + TS - 1) / TS), dim3(256), 0, stream>>>(seq_emb, emb, out);
}

// Round 2
// 952.584 us; speedup vs baseline: 1.2169x; 1.2169x over previous
//
#include <hip/hip_runtime.h>
#include <cmath>

#define HH 256
#define NB 32
#define LSEQ 50
#define BB 512
#define VOC 100000

typedef __attribute__((ext_vector_type(8))) short short8;
typedef __attribute__((ext_vector_type(4))) float f32x4;

static __device__ __forceinline__ unsigned short f2bf(float x) {
  unsigned u = __builtin_bit_cast(unsigned, x);
  u = (u + 0x7fff + ((u >> 16) & 1)) >> 16;   // round-to-nearest-even
  return (unsigned short)u;
}
static __device__ __forceinline__ float bf2f(unsigned short h) {
  unsigned u = ((unsigned)h) << 16;
  return __builtin_bit_cast(float, u);
}

// ---------------- generic tiled fp32 GEMM: C[M,N] = A[M,K]@W[K,N] + bias[N]
#define TS 64
#define KSTEP 16
#define LDP 68

__global__ __launch_bounds__(256) void gemm_nn_bias(
    const float* __restrict__ A, const float* __restrict__ W,
    const float* __restrict__ bias, float* __restrict__ C,
    int M, int N, int K)
{
  __shared__ float As[KSTEP * LDP];
  __shared__ float Ws[KSTEP * LDP];
  const int tid = threadIdx.x;
  const int tx = tid & 15, ty = tid >> 4;
  const int n0 = blockIdx.x * TS, m0 = blockIdx.y * TS;

  const int lkk = tid & 15, lm = tid >> 4;
  const int ln  = tid & 63, lkr = tid >> 6;

  float acc[4][4] = {};

  for (int k0 = 0; k0 < K; k0 += KSTEP) {
#pragma unroll
    for (int r = 0; r < 4; ++r)
      As[lkk * LDP + lm + r * 16] = A[(m0 + lm + r * 16) * K + k0 + lkk];
#pragma unroll
    for (int r = 0; r < 4; ++r)
      Ws[(lkr + r * 4) * LDP + ln] = W[(k0 + lkr + r * 4) * N + n0 + ln];
    __syncthreads();
#pragma unroll
    for (int kk = 0; kk < KSTEP; ++kk) {
      const float4 a4 = *(const float4*)(As + kk * LDP + ty * 4);
      const float4 w4 = *(const float4*)(Ws + kk * LDP + tx * 4);
      const float av[4] = {a4.x, a4.y, a4.z, a4.w};
      const float wv[4] = {w4.x, w4.y, w4.z, w4.w};
#pragma unroll
      for (int i = 0; i < 4; ++i)
#pragma unroll
        for (int j = 0; j < 4; ++j)
          acc[i][j] += av[i] * wv[j];
    }
    __syncthreads();
  }

  const float4 b4 = *(const float4*)(bias + n0 + tx * 4);
  const float bv[4] = {b4.x, b4.y, b4.z, b4.w};
#pragma unroll
  for (int i = 0; i < 4; ++i) {
    float4 o;
    o.x = acc[i][0] + bv[0];
    o.y = acc[i][1] + bv[1];
    o.z = acc[i][2] + bv[2];
    o.w = acc[i][3] + bv[3];
    *(float4*)(C + (m0 + ty * 4 + i) * N + n0 + tx * 4) = o;
  }
}

// ---------------- split seq_emb into bf16 hi/lo
__global__ void split_seq(const float* __restrict__ s, unsigned short* __restrict__ hi,
                          unsigned short* __restrict__ lo, int n)
{
  const int i = blockIdx.x * blockDim.x + threadIdx.x;
  if (i >= n) return;
  const float x = s[i];
  const unsigned short h = f2bf(x);
  hi[i] = h;
  lo[i] = f2bf(x - bf2f(h));
}

// ---------------- scores = seq_emb[512,256] @ emb[1:][VOC,256]^T via split-bf16 MFMA
// Block: 256 thr (4 waves), Vtile=64, all M=512 per block (emb fetched exactly once).
#define VT 64
#define ELD 264   // LDS row stride in bf16 (264*2=528 B; bank(row)=4*row%32 -> 2-way, free)

__global__ __launch_bounds__(256, 2) void scorer_mfma(
    const unsigned short* __restrict__ seq_hi,
    const unsigned short* __restrict__ seq_lo,
    const float* __restrict__ emb,
    float* __restrict__ out)
{
  __shared__ unsigned short ehi[VT * ELD];
  __shared__ unsigned short elo[VT * ELD];
  const int tid = threadIdx.x;
  const int v0 = blockIdx.x * VT;

  // stage emb tile [VT][256] fp32 -> bf16 hi/lo in LDS (once per block)
#pragma unroll
  for (int i = 0; i < 16; ++i) {
    const int idx4 = tid + i * 256;            // float4 index in tile
    const int row = idx4 >> 6, c4 = idx4 & 63; // 64 float4 per row
    const int v = v0 + row;
    float4 x = make_float4(0.f, 0.f, 0.f, 0.f);
    if (v < VOC) x = ((const float4*)(emb + (size_t)(v + 1) * HH))[c4];
    const unsigned short h0 = f2bf(x.x), h1 = f2bf(x.y), h2 = f2bf(x.z), h3 = f2bf(x.w);
    const unsigned short l0 = f2bf(x.x - bf2f(h0)), l1 = f2bf(x.y - bf2f(h1));
    const unsigned short l2 = f2bf(x.z - bf2f(h2)), l3 = f2bf(x.w - bf2f(h3));
    uint2 ph, pl;
    ph.x = (unsigned)h0 | ((unsigned)h1 << 16);
    ph.y = (unsigned)h2 | ((unsigned)h3 << 16);
    pl.x = (unsigned)l0 | ((unsigned)l1 << 16);
    pl.y = (unsigned)l2 | ((unsigned)l3 << 16);
    *(uint2*)&ehi[row * ELD + c4 * 4] = ph;
    *(uint2*)&elo[row * ELD + c4 * 4] = pl;
  }
  __syncthreads();

  const int lane = tid & 63, wave = tid >> 6;
  const int quad = lane >> 4, l16 = lane & 15;
  const int mwave = wave * 128;   // each wave owns 128 m-rows (8 subtiles)

  f32x4 acc[8][4];
#pragma unroll
  for (int ms = 0; ms < 8; ++ms)
#pragma unroll
    for (int vs = 0; vs < 4; ++vs)
#pragma unroll
      for (int r = 0; r < 4; ++r) acc[ms][vs][r] = 0.f;

  for (int k0 = 0; k0 < HH; k0 += 32) {
    short8 bh[4], bl[4];
#pragma unroll
    for (int vs = 0; vs < 4; ++vs) {
      const int off = (vs * 16 + l16) * ELD + k0 + quad * 8;
      bh[vs] = *(const short8*)&ehi[off];
      bl[vs] = *(const short8*)&elo[off];
    }
#pragma unroll
    for (int ms = 0; ms < 8; ++ms) {
      const int m = mwave + ms * 16 + l16;
      const int aoff = m * HH + k0 + quad * 8;
      const short8 ah = *(const short8*)&seq_hi[aoff];
      const short8 al = *(const short8*)&seq_lo[aoff];
#pragma unroll
      for (int vs = 0; vs < 4; ++vs) {
        acc[ms][vs] = __builtin_amdgcn_mfma_f32_16x16x32_bf16(ah, bh[vs], acc[ms][vs], 0, 0, 0);
        acc[ms][vs] = __builtin_amdgcn_mfma_f32_16x16x32_bf16(ah, bl[vs], acc[ms][vs], 0, 0, 0);
        acc[ms][vs] = __builtin_amdgcn_mfma_f32_16x16x32_bf16(al, bh[vs], acc[ms][vs], 0, 0, 0);
      }
    }
  }

  // D layout: col = lane&15 (v), row = quad*4 + r (m)
#pragma unroll
  for (int ms = 0; ms < 8; ++ms) {
    const int mrow = mwave + ms * 16 + quad * 4;
#pragma unroll
    for (int vs = 0; vs < 4; ++vs) {
      const int v = v0 + vs * 16 + l16;
      if (v < VOC) {
#pragma unroll
        for (int r = 0; r < 4; ++r)
          out[(size_t)(mrow + r) * VOC + v] = acc[ms][vs][r];
      }
    }
  }
}

// ---------------- h0[b,n,:] = emb[items[b,n],:]
__global__ void gather_h0(const int* __restrict__ items, const float* __restrict__ emb,
                          float* __restrict__ h0, int total4)
{
  const int e = blockIdx.x * blockDim.x + threadIdx.x;
  if (e >= total4) return;
  const int row = e >> 6, c = e & 63;
  const int it = items[row];
  ((float4*)h0)[e] = ((const float4*)emb)[it * 64 + c];
}

// ---------------- a_cat = [A_in@hin, A_out@hout]
__global__ __launch_bounds__(256) void msg_kernel(
    const float* __restrict__ A, const float* __restrict__ hin,
    const float* __restrict__ hout, float* __restrict__ acat)
{
  const int b = blockIdx.x;
  const int tid = threadIdx.x;
  __shared__ float Ash[NB * 64];
#pragma unroll
  for (int r = 0; r < 8; ++r)
    Ash[tid + r * 256] = A[b * (NB * 2 * NB) + tid + r * 256];
  float hi[NB], ho[NB];
  const float* hinb = hin + b * NB * HH + tid;
  const float* houtb = hout + b * NB * HH + tid;
#pragma unroll
  for (int j = 0; j < NB; ++j) {
    hi[j] = hinb[j * HH];
    ho[j] = houtb[j * HH];
  }
  __syncthreads();
  for (int i = 0; i < NB; ++i) {
    float si = 0.f, so = 0.f;
#pragma unroll
    for (int j = 0; j < NB; ++j) {
      si += Ash[i * 64 + j] * hi[j];
      so += Ash[i * 64 + 32 + j] * ho[j];
    }
    acat[b * (NB * 2 * HH) + i * (2 * HH) + tid] = si;
    acat[b * (NB * 2 * HH) + i * (2 * HH) + HH + tid] = so;
  }
}

// ---------------- GRU cell elementwise; h updated in place
__global__ void gru_kernel(const float* __restrict__ gi, const float* __restrict__ gh,
                           float* __restrict__ h, int total)
{
  const int idx = blockIdx.x * blockDim.x + threadIdx.x;
  if (idx >= total) return;
  const int row = idx >> 8, k = idx & 255;
  const float* gir = gi + row * 768;
  const float* ghr = gh + row * 768;
  const float ir = gir[k], iz = gir[k + 256], inn = gir[k + 512];
  const float hr = ghr[k], hz = ghr[k + 256], hn = ghr[k + 512];
  const float r = 1.f / (1.f + expf(-(ir + hr)));
  const float z = 1.f / (1.f + expf(-(iz + hz)));
  const float n = tanhf(inn + r * hn);
  const float h0v = h[idx];
  h[idx] = n + z * (h0v - n);
}

// ---------------- h_seqs gather + tail
__global__ __launch_bounds__(256) void seq_gather(
    const int* __restrict__ seq_alias, const int* __restrict__ mask,
    const float* __restrict__ h, float* __restrict__ h_seqs, float* __restrict__ h_tail)
{
  const int b = blockIdx.x, tid = threadIdx.x;
  __shared__ int tail_sh;
  if (tid == 0) {
    int s = 0;
    for (int l = 0; l < LSEQ; ++l) s += mask[b * LSEQ + l];
    tail_sh = s - 1;
  }
  __syncthreads();
  const int tail = tail_sh;
  for (int l = 0; l < LSEQ; ++l) {
    const int al = seq_alias[b * LSEQ + l];
    const float v = h[(b * NB + al) * HH + tid];
    h_seqs[(b * LSEQ + l) * HH + tid] = v;
    if (l == tail) h_tail[b * HH + tid] = v;
  }
}

// ---------------- attention pooling
__global__ __launch_bounds__(256) void attn_kernel(
    const float* __restrict__ q1, const float* __restrict__ q2,
    const float* __restrict__ fc3_w, const float* __restrict__ h_seqs,
    const int* __restrict__ mask, float* __restrict__ seq_emb)
{
  const int b = blockIdx.x, k = threadIdx.x;
  __shared__ float red[4];
  __shared__ float alpha_sh;
  const float q1k = q1[b * HH + k];
  const float w3 = fc3_w[k];
  float acc = 0.f;
  for (int l = 0; l < LSEQ; ++l) {
    const float q2v = q2[(b * LSEQ + l) * HH + k];
    float v = (1.f / (1.f + expf(-(q1k + q2v)))) * w3;
#pragma unroll
    for (int off = 32; off > 0; off >>= 1) v += __shfl_down(v, off, 64);
    if ((k & 63) == 0) red[k >> 6] = v;
    __syncthreads();
    if (k == 0) alpha_sh = red[0] + red[1] + red[2] + red[3];
    __syncthreads();
    const float alpha = alpha_sh;
    if (mask[b * LSEQ + l]) acc += alpha * h_seqs[(b * LSEQ + l) * HH + k];
  }
  seq_emb[b * HH + k] = acc;
}

extern "C" void kernel_launch(void* const* d_in, const int* in_sizes, int n_in,
                              void* d_out, int out_size, void* d_ws, size_t ws_size,
                              hipStream_t stream)
{
  const float* A      = (const float*)d_in[0];
  const int* items    = (const int*)d_in[1];
  const int* seq_al   = (const int*)d_in[2];
  const int* mask     = (const int*)d_in[3];
  const float* emb    = (const float*)d_in[4];
  const float* W_in   = (const float*)d_in[5];
  const float* b_in   = (const float*)d_in[6];
  const float* W_out  = (const float*)d_in[7];
  const float* b_out  = (const float*)d_in[8];
  const float* W_ih   = (const float*)d_in[9];
  const float* b_ih   = (const float*)d_in[10];
  const float* W_hh   = (const float*)d_in[11];
  const float* b_hh   = (const float*)d_in[12];
  const float* fc1_w  = (const float*)d_in[13];
  const float* fc1_b  = (const float*)d_in[14];
  const float* fc2_w  = (const float*)d_in[15];
  const float* fc2_b  = (const float*)d_in[16];
  const float* fc3_w  = (const float*)d_in[17];
  float* out = (float*)d_out;

  float* ws = (float*)d_ws;
  float* h0      = ws;                 // 4,194,304 floats
  float* q1      = ws + 4194304;       // 131,072
  float* h_tail  = ws + 4325376;       // 131,072
  float* seq_emb = ws + 4456448;       // 131,072
  unsigned short* seq_hi = (unsigned short*)(ws + 4587520);  // 131,072 ushorts
  unsigned short* seq_lo = (unsigned short*)(ws + 4653056);  // 131,072 ushorts

  float* gi     = out;                 // 12,582,912
  float* gh     = out + 12582912;      // 12,582,912
  float* a_cat  = out + 25165824;      //  8,388,608
  float* hin    = out + 33554432;      //  4,194,304
  float* hout   = out + 37748736;      //  4,194,304
  float* h_seqs = out + 12582912;      // reuse gh region post-GRU
  float* q2     = out;                 // reuse gi region post-GRU

  const int MR = BB * NB;  // 16384 rows

  gather_h0<<<dim3((MR * 64 + 255) / 256), dim3(256), 0, stream>>>(items, emb, h0, MR * 64);

  gemm_nn_bias<<<dim3(HH / TS, MR / TS), dim3(256), 0, stream>>>(h0, W_in, b_in, hin, MR, HH, HH);
  gemm_nn_bias<<<dim3(HH / TS, MR / TS), dim3(256), 0, stream>>>(h0, W_out, b_out, hout, MR, HH, HH);

  msg_kernel<<<dim3(BB), dim3(256), 0, stream>>>(A, hin, hout, a_cat);

  gemm_nn_bias<<<dim3(768 / TS, MR / TS), dim3(256), 0, stream>>>(h0, W_hh, b_hh, gh, MR, 768, HH);
  gemm_nn_bias<<<dim3(768 / TS, MR / TS), dim3(256), 0, stream>>>(a_cat, W_ih, b_ih, gi, MR, 768, 2 * HH);

  gru_kernel<<<dim3((MR * HH + 255) / 256), dim3(256), 0, stream>>>(gi, gh, h0, MR * HH);

  seq_gather<<<dim3(BB), dim3(256), 0, stream>>>(seq_al, mask, h0, h_seqs, h_tail);

  gemm_nn_bias<<<dim3(HH / TS, (BB * LSEQ) / TS), dim3(256), 0, stream>>>(h_seqs, fc2_w, fc2_b, q2, BB * LSEQ, HH, HH);
  gemm_nn_bias<<<dim3(HH / TS, BB / TS), dim3(256), 0, stream>>>(h_tail, fc1_w, fc1_b, q1, BB, HH, HH);

  attn_kernel<<<dim3(BB), dim3(256), 0, stream>>>(q1, q2, fc3_w, h_seqs, mask, seq_emb);

  // scores via split-bf16 MFMA
  split_seq<<<dim3((BB * HH + 255) / 256), dim3(256), 0, stream>>>(seq_emb, seq_hi, seq_lo, BB * HH);
  scorer_mfma<<<dim3((VOC + VT - 1) / VT), dim3(256), 0, stream>>>(seq_hi, seq_lo, emb, out);
}

// Round 3
// 712.952 us; speedup vs baseline: 1.6259x; 1.3361x over previous
//
#include <hip/hip_runtime.h>
#include <cmath>

#define HH 256
#define NB 32
#define LSEQ 50
#define BB 512
#define VOC 100000

typedef __attribute__((ext_vector_type(8))) short short8;
typedef __attribute__((ext_vector_type(4))) float f32x4;

static __device__ __forceinline__ unsigned short f2bf(float x) {
  unsigned u = __builtin_bit_cast(unsigned, x);
  u = (u + 0x7fff + ((u >> 16) & 1)) >> 16;   // round-to-nearest-even
  return (unsigned short)u;
}
static __device__ __forceinline__ float bf2f(unsigned short h) {
  unsigned u = ((unsigned)h) << 16;
  return __builtin_bit_cast(float, u);
}
static __device__ __forceinline__ uint2 pack_hi4(float4 x, uint2& pl) {
  const unsigned short h0 = f2bf(x.x), h1 = f2bf(x.y), h2 = f2bf(x.z), h3 = f2bf(x.w);
  const unsigned short l0 = f2bf(x.x - bf2f(h0)), l1 = f2bf(x.y - bf2f(h1));
  const unsigned short l2 = f2bf(x.z - bf2f(h2)), l3 = f2bf(x.w - bf2f(h3));
  uint2 ph;
  ph.x = (unsigned)h0 | ((unsigned)h1 << 16);
  ph.y = (unsigned)h2 | ((unsigned)h3 << 16);
  pl.x = (unsigned)l0 | ((unsigned)l1 << 16);
  pl.y = (unsigned)l2 | ((unsigned)l3 << 16);
  return ph;
}

// ============ prep: transpose + bf16-split weights into ws ============
// blocks [0,1280): Wt_all[n][k] = [W_in|W_out|W_hh][k][n], b_all
// blocks [1280,2048): WihT[n][k] (768x512) ; blocks [2048,2304): fc2T[n][k]
__global__ void prep_weights(const float* __restrict__ W_in, const float* __restrict__ b_in,
                             const float* __restrict__ W_out, const float* __restrict__ b_out,
                             const float* __restrict__ W_hh, const float* __restrict__ b_hh,
                             const float* __restrict__ W_ih, const float* __restrict__ fc2_w,
                             unsigned short* __restrict__ Wt_all, float* __restrict__ b_all,
                             unsigned short* __restrict__ WihT, unsigned short* __restrict__ fc2T)
{
  const int bid = blockIdx.x, k = threadIdx.x;
  if (bid < 1280) {
    const float* src; const float* bsrc; int col, nc;
    if (bid < 256)      { src = W_in;  bsrc = b_in;  col = bid;       nc = 256; }
    else if (bid < 512) { src = W_out; bsrc = b_out; col = bid - 256; nc = 256; }
    else                { src = W_hh;  bsrc = b_hh;  col = bid - 512; nc = 768; }
    Wt_all[bid * 256 + k] = f2bf(src[k * nc + col]);
    if (k == 0) b_all[bid] = bsrc[col];
  } else if (bid < 2048) {
    const int n = bid - 1280;
    WihT[n * 512 + k]       = f2bf(W_ih[k * 768 + n]);
    WihT[n * 512 + k + 256] = f2bf(W_ih[(k + 256) * 768 + n]);
  } else {
    const int n = bid - 2048;
    fc2T[n * 256 + k] = f2bf(fc2_w[k * 256 + n]);
  }
}

// ============ A-split bf16 MFMA GEMM: C[M,N](ldc) = (Ah+Al)[M,K] @ Bt[N,K]^T + bias ============
// 256 thr (4 waves 2x2), tile 128x128, BK=32. LDS layout [quad][row][8] us, packed.
__global__ __launch_bounds__(256, 3) void gemm_asplit_nt(
    const unsigned short* __restrict__ Ah, const unsigned short* __restrict__ Al,
    const unsigned short* __restrict__ Bt, const float* __restrict__ bias,
    float* __restrict__ C, int N, int K, int ldc)
{
  __shared__ unsigned short sAh[4 * 128 * 8];
  __shared__ unsigned short sAl[4 * 128 * 8];
  __shared__ unsigned short sB [4 * 128 * 8];
  const int tid = threadIdx.x;
  const int n0 = blockIdx.x * 128, m0 = blockIdx.y * 128;
  const int lane = tid & 63, wave = tid >> 6;
  const int quad = lane >> 4, l16 = lane & 15;
  const int wm = (wave >> 1) * 64, wn = (wave & 1) * 64;

  f32x4 acc[4][4];
#pragma unroll
  for (int i = 0; i < 4; ++i)
#pragma unroll
    for (int j = 0; j < 4; ++j)
#pragma unroll
      for (int r = 0; r < 4; ++r) acc[i][j][r] = 0.f;

  const int c0 = tid, c1 = tid + 256;          // chunk ids (512 chunks of 16B per tile)
  const int q0 = c0 >> 7, r0 = c0 & 127;
  const int q1c = c1 >> 7, r1 = c1 & 127;

  for (int k0 = 0; k0 < K; k0 += 32) {
    const size_t ga0 = (size_t)(m0 + r0) * K + k0 + q0 * 8;
    const size_t ga1 = (size_t)(m0 + r1) * K + k0 + q1c * 8;
    const size_t gb0 = (size_t)(n0 + r0) * K + k0 + q0 * 8;
    const size_t gb1 = (size_t)(n0 + r1) * K + k0 + q1c * 8;
    *(uint4*)&sAh[c0 * 8] = *(const uint4*)&Ah[ga0];
    *(uint4*)&sAh[c1 * 8] = *(const uint4*)&Ah[ga1];
    *(uint4*)&sAl[c0 * 8] = *(const uint4*)&Al[ga0];
    *(uint4*)&sAl[c1 * 8] = *(const uint4*)&Al[ga1];
    *(uint4*)&sB [c0 * 8] = *(const uint4*)&Bt[gb0];
    *(uint4*)&sB [c1 * 8] = *(const uint4*)&Bt[gb1];
    __syncthreads();

    short8 fah[4], fal[4];
#pragma unroll
    for (int ms = 0; ms < 4; ++ms) {
      const int row = wm + ms * 16 + l16;
      fah[ms] = *(const short8*)&sAh[(quad * 128 + row) * 8];
      fal[ms] = *(const short8*)&sAl[(quad * 128 + row) * 8];
    }
#pragma unroll
    for (int ns = 0; ns < 4; ++ns) {
      const int col = wn + ns * 16 + l16;
      const short8 fb = *(const short8*)&sB[(quad * 128 + col) * 8];
#pragma unroll
      for (int ms = 0; ms < 4; ++ms) {
        acc[ms][ns] = __builtin_amdgcn_mfma_f32_16x16x32_bf16(fah[ms], fb, acc[ms][ns], 0, 0, 0);
        acc[ms][ns] = __builtin_amdgcn_mfma_f32_16x16x32_bf16(fal[ms], fb, acc[ms][ns], 0, 0, 0);
      }
    }
    __syncthreads();
  }

#pragma unroll
  for (int ns = 0; ns < 4; ++ns) {
    const int n = n0 + wn + ns * 16 + l16;
    const float bv = bias[n];
#pragma unroll
    for (int ms = 0; ms < 4; ++ms) {
      const int mrow = m0 + wm + ms * 16 + quad * 4;
#pragma unroll
      for (int r = 0; r < 4; ++r)
        C[(size_t)(mrow + r) * ldc + n] = acc[ms][ns][r] + bv;
    }
  }
}

// ============ fp32 tiled GEMM kept for tiny q1 ============
#define TS 64
#define KSTEP 16
#define LDPF 68
__global__ __launch_bounds__(256) void gemm_nn_bias(
    const float* __restrict__ A, const float* __restrict__ W,
    const float* __restrict__ bias, float* __restrict__ C,
    int M, int N, int K)
{
  __shared__ float As[KSTEP * LDPF];
  __shared__ float Ws[KSTEP * LDPF];
  const int tid = threadIdx.x;
  const int tx = tid & 15, ty = tid >> 4;
  const int n0 = blockIdx.x * TS, m0 = blockIdx.y * TS;
  const int lkk = tid & 15, lm = tid >> 4;
  const int ln  = tid & 63, lkr = tid >> 6;
  float acc[4][4] = {};
  for (int k0 = 0; k0 < K; k0 += KSTEP) {
#pragma unroll
    for (int r = 0; r < 4; ++r)
      As[lkk * LDPF + lm + r * 16] = A[(m0 + lm + r * 16) * K + k0 + lkk];
#pragma unroll
    for (int r = 0; r < 4; ++r)
      Ws[(lkr + r * 4) * LDPF + ln] = W[(k0 + lkr + r * 4) * N + n0 + ln];
    __syncthreads();
#pragma unroll
    for (int kk = 0; kk < KSTEP; ++kk) {
      const float4 a4 = *(const float4*)(As + kk * LDPF + ty * 4);
      const float4 w4 = *(const float4*)(Ws + kk * LDPF + tx * 4);
      const float av[4] = {a4.x, a4.y, a4.z, a4.w};
      const float wv[4] = {w4.x, w4.y, w4.z, w4.w};
#pragma unroll
      for (int i = 0; i < 4; ++i)
#pragma unroll
        for (int j = 0; j < 4; ++j)
          acc[i][j] += av[i] * wv[j];
    }
    __syncthreads();
  }
  const float4 b4 = *(const float4*)(bias + n0 + tx * 4);
  const float bv[4] = {b4.x, b4.y, b4.z, b4.w};
#pragma unroll
  for (int i = 0; i < 4; ++i) {
    float4 o;
    o.x = acc[i][0] + bv[0]; o.y = acc[i][1] + bv[1];
    o.z = acc[i][2] + bv[2]; o.w = acc[i][3] + bv[3];
    *(float4*)(C + (m0 + ty * 4 + i) * N + n0 + tx * 4) = o;
  }
}

// ============ h0 = emb[items] (+ bf16 split) ============
__global__ void gather_h0(const int* __restrict__ items, const float* __restrict__ emb,
                          float* __restrict__ h0, unsigned short* __restrict__ h0h,
                          unsigned short* __restrict__ h0l, int total4)
{
  const int e = blockIdx.x * blockDim.x + threadIdx.x;
  if (e >= total4) return;
  const int row = e >> 6, c = e & 63;
  const int it = items[row];
  const float4 x = ((const float4*)emb)[it * 64 + c];
  ((float4*)h0)[e] = x;
  uint2 pl;
  const uint2 ph = pack_hi4(x, pl);
  *(uint2*)&h0h[e * 4] = ph;
  *(uint2*)&h0l[e * 4] = pl;
}

// ============ a_cat = [A_in@hin, A_out@hout] -> bf16 hi/lo ============
__global__ __launch_bounds__(256) void msg_kernel(
    const float* __restrict__ A, const float* __restrict__ C1,
    unsigned short* __restrict__ ach, unsigned short* __restrict__ acl)
{
  const int b = blockIdx.x;
  const int tid = threadIdx.x;
  __shared__ float Ash[NB * 64];
#pragma unroll
  for (int r = 0; r < 8; ++r)
    Ash[tid + r * 256] = A[b * (NB * 2 * NB) + tid + r * 256];
  float hi[NB], ho[NB];
#pragma unroll
  for (int j = 0; j < NB; ++j) {
    hi[j] = C1[(size_t)(b * NB + j) * 1280 + tid];
    ho[j] = C1[(size_t)(b * NB + j) * 1280 + 256 + tid];
  }
  __syncthreads();
  for (int i = 0; i < NB; ++i) {
    float si = 0.f, so = 0.f;
#pragma unroll
    for (int j = 0; j < NB; ++j) {
      si += Ash[i * 64 + j] * hi[j];
      so += Ash[i * 64 + 32 + j] * ho[j];
    }
    const int idx = (b * NB + i) * 512 + tid;
    const unsigned short sh = f2bf(si);
    ach[idx] = sh; acl[idx] = f2bf(si - bf2f(sh));
    const unsigned short oh = f2bf(so);
    ach[idx + 256] = oh; acl[idx + 256] = f2bf(so - bf2f(oh));
  }
}

// ============ GRU elementwise; h updated in place (gh lives in C1[:,512:1280]) ============
__global__ void gru_kernel(const float* __restrict__ gi, const float* __restrict__ C1,
                           float* __restrict__ h, int total)
{
  const int idx = blockIdx.x * blockDim.x + threadIdx.x;
  if (idx >= total) return;
  const int row = idx >> 8, k = idx & 255;
  const float* gir = gi + (size_t)row * 768;
  const float* ghr = C1 + (size_t)row * 1280 + 512;
  const float ir = gir[k], iz = gir[k + 256], inn = gir[k + 512];
  const float hr = ghr[k], hz = ghr[k + 256], hn = ghr[k + 512];
  const float r = 1.f / (1.f + expf(-(ir + hr)));
  const float z = 1.f / (1.f + expf(-(iz + hz)));
  const float n = tanhf(inn + r * hn);
  const float h0v = h[idx];
  h[idx] = n + z * (h0v - n);
}

// ============ h_seqs gather (+ split) + tail ============
__global__ __launch_bounds__(256) void seq_gather(
    const int* __restrict__ seq_alias, const int* __restrict__ mask,
    const float* __restrict__ h, float* __restrict__ h_seqs,
    unsigned short* __restrict__ hsh, unsigned short* __restrict__ hsl,
    float* __restrict__ h_tail)
{
  const int b = blockIdx.x, tid = threadIdx.x;
  __shared__ int tail_sh;
  if (tid == 0) {
    int s = 0;
    for (int l = 0; l < LSEQ; ++l) s += mask[b * LSEQ + l];
    tail_sh = s - 1;
  }
  __syncthreads();
  const int tail = tail_sh;
  for (int l = 0; l < LSEQ; ++l) {
    const int al = seq_alias[b * LSEQ + l];
    const float v = h[(size_t)(b * NB + al) * HH + tid];
    const int idx = (b * LSEQ + l) * HH + tid;
    h_seqs[idx] = v;
    const unsigned short vh = f2bf(v);
    hsh[idx] = vh; hsl[idx] = f2bf(v - bf2f(vh));
    if (l == tail) h_tail[b * HH + tid] = v;
  }
}

// ============ attention pooling ============
__global__ __launch_bounds__(256) void attn_kernel(
    const float* __restrict__ q1, const float* __restrict__ q2,
    const float* __restrict__ fc3_w, const float* __restrict__ h_seqs,
    const int* __restrict__ mask, float* __restrict__ seq_emb)
{
  const int b = blockIdx.x, k = threadIdx.x;
  __shared__ float red[4];
  __shared__ float alpha_sh;
  const float q1k = q1[b * HH + k];
  const float w3 = fc3_w[k];
  float acc = 0.f;
  for (int l = 0; l < LSEQ; ++l) {
    const float q2v = q2[(size_t)(b * LSEQ + l) * HH + k];
    float v = (1.f / (1.f + expf(-(q1k + q2v)))) * w3;
#pragma unroll
    for (int off = 32; off > 0; off >>= 1) v += __shfl_down(v, off, 64);
    if ((k & 63) == 0) red[k >> 6] = v;
    __syncthreads();
    if (k == 0) alpha_sh = red[0] + red[1] + red[2] + red[3];
    __syncthreads();
    const float alpha = alpha_sh;
    if (mask[b * LSEQ + l]) acc += alpha * h_seqs[(size_t)(b * LSEQ + l) * HH + k];
  }
  seq_emb[b * HH + k] = acc;
}

// ============ split seq_emb ============
__global__ void split_seq(const float* __restrict__ s, unsigned short* __restrict__ hi,
                          unsigned short* __restrict__ lo, int n)
{
  const int i = blockIdx.x * blockDim.x + threadIdx.x;
  if (i >= n) return;
  const float x = s[i];
  const unsigned short h = f2bf(x);
  hi[i] = h;
  lo[i] = f2bf(x - bf2f(h));
}

// ============ scores: split-bf16 3-product MFMA, k-phased LDS, m-split grid ============
#define ELD2 136  // us row stride (272 B): 16B-aligned, 2-way bank alias (free)
__global__ __launch_bounds__(256, 3) void scorer_mfma(
    const unsigned short* __restrict__ seq_hi,
    const unsigned short* __restrict__ seq_lo,
    const float* __restrict__ emb,
    float* __restrict__ out)
{
  __shared__ unsigned short ehi[64 * ELD2];
  __shared__ unsigned short elo[64 * ELD2];
  const int tid = threadIdx.x;
  const int v0 = blockIdx.x * 64;
  const int m0 = blockIdx.y * 256;
  const int lane = tid & 63, wave = tid >> 6;
  const int quad = lane >> 4, l16 = lane & 15;
  const int mwave = m0 + wave * 64;

  f32x4 acc[4][4];
#pragma unroll
  for (int i = 0; i < 4; ++i)
#pragma unroll
    for (int j = 0; j < 4; ++j)
#pragma unroll
      for (int r = 0; r < 4; ++r) acc[i][j][r] = 0.f;

  for (int p = 0; p < 2; ++p) {
    // stage emb[v0..v0+64][p*128..+128] fp32 -> bf16 hi/lo
#pragma unroll
    for (int i = 0; i < 8; ++i) {
      const int idx4 = tid + i * 256;
      const int row = idx4 >> 5, c4 = idx4 & 31;
      const int v = v0 + row;
      float4 x = make_float4(0.f, 0.f, 0.f, 0.f);
      if (v < VOC) x = *(const float4*)&emb[(size_t)(v + 1) * HH + p * 128 + c4 * 4];
      uint2 pl;
      const uint2 ph = pack_hi4(x, pl);
      *(uint2*)&ehi[row * ELD2 + c4 * 4] = ph;
      *(uint2*)&elo[row * ELD2 + c4 * 4] = pl;
    }
    __syncthreads();

#pragma unroll
    for (int ks = 0; ks < 4; ++ks) {
      const int kk = ks * 32;
      short8 bh[4], bl[4];
#pragma unroll
      for (int vs = 0; vs < 4; ++vs) {
        const int off = (vs * 16 + l16) * ELD2 + kk + quad * 8;
        bh[vs] = *(const short8*)&ehi[off];
        bl[vs] = *(const short8*)&elo[off];
      }
#pragma unroll
      for (int ms = 0; ms < 4; ++ms) {
        const int m = mwave + ms * 16 + l16;
        const int aoff = m * HH + p * 128 + kk + quad * 8;
        const short8 ah = *(const short8*)&seq_hi[aoff];
        const short8 al = *(const short8*)&seq_lo[aoff];
#pragma unroll
        for (int vs = 0; vs < 4; ++vs) {
          acc[ms][vs] = __builtin_amdgcn_mfma_f32_16x16x32_bf16(ah, bh[vs], acc[ms][vs], 0, 0, 0);
          acc[ms][vs] = __builtin_amdgcn_mfma_f32_16x16x32_bf16(ah, bl[vs], acc[ms][vs], 0, 0, 0);
          acc[ms][vs] = __builtin_amdgcn_mfma_f32_16x16x32_bf16(al, bh[vs], acc[ms][vs], 0, 0, 0);
        }
      }
    }
    __syncthreads();
  }

#pragma unroll
  for (int ms = 0; ms < 4; ++ms) {
    const int mrow = mwave + ms * 16 + quad * 4;
#pragma unroll
    for (int vs = 0; vs < 4; ++vs) {
      const int v = v0 + vs * 16 + l16;
      if (v < VOC) {
#pragma unroll
        for (int r = 0; r < 4; ++r)
          out[(size_t)(mrow + r) * VOC + v] = acc[ms][vs][r];
      }
    }
  }
}

extern "C" void kernel_launch(void* const* d_in, const int* in_sizes, int n_in,
                              void* d_out, int out_size, void* d_ws, size_t ws_size,
                              hipStream_t stream)
{
  const float* A      = (const float*)d_in[0];
  const int* items    = (const int*)d_in[1];
  const int* seq_al   = (const int*)d_in[2];
  const int* mask     = (const int*)d_in[3];
  const float* emb    = (const float*)d_in[4];
  const float* W_in   = (const float*)d_in[5];
  const float* b_in   = (const float*)d_in[6];
  const float* W_out  = (const float*)d_in[7];
  const float* b_out  = (const float*)d_in[8];
  const float* W_ih   = (const float*)d_in[9];
  const float* b_ih   = (const float*)d_in[10];
  const float* W_hh   = (const float*)d_in[11];
  const float* b_hh   = (const float*)d_in[12];
  const float* fc1_w  = (const float*)d_in[13];
  const float* fc1_b  = (const float*)d_in[14];
  const float* fc2_w  = (const float*)d_in[15];
  const float* fc2_b  = (const float*)d_in[16];
  const float* fc3_w  = (const float*)d_in[17];
  float* out = (float*)d_out;

  // ---- ws layout (floats) ----
  float* ws = (float*)d_ws;
  float* h0      = ws;                  // 4,194,304 (h after GRU, in place)
  float* q1      = ws + 4194304;        // 131,072
  float* h_tail  = ws + 4325376;        // 131,072
  float* seq_emb = ws + 4456448;        // 131,072
  unsigned short* seq_hi = (unsigned short*)(ws + 4587520);  // 131,072 us
  unsigned short* seq_lo = (unsigned short*)(ws + 4653056);
  unsigned short* Wt_all = (unsigned short*)(ws + 4718592);  // 327,680 us
  unsigned short* WihT   = (unsigned short*)(ws + 4882432);  // 393,216 us
  unsigned short* fc2T   = (unsigned short*)(ws + 5079040);  // 65,536 us
  float* b_all   = ws + 5111808;        // 1,280

  // ---- d_out scratch (liveness-ordered; scorer overwrites all) ----
  float* C1 = out;                                        // 16384x1280 fp32
  unsigned short* acat_h = (unsigned short*)(out + 20971520);  // 16384x512 us
  unsigned short* acat_l = (unsigned short*)(out + 25165824);
  float* gi = out + 29360128;                             // 16384x768 fp32
  unsigned short* h0h = (unsigned short*)(out + 41943040);     // 16384x256 us
  unsigned short* h0l = (unsigned short*)(out + 44040192);
  // post-GRU (C1/acat/gi/h0h dead):
  float* h_seqs = out;                                    // 25600x256 fp32
  unsigned short* hs_h = (unsigned short*)(out + 6553600);
  unsigned short* hs_l = (unsigned short*)(out + 9830400);
  float* q2 = out + 13107200;                             // 25600x256 fp32

  const int MR = BB * NB;  // 16384

  prep_weights<<<dim3(2304), dim3(256), 0, stream>>>(
      W_in, b_in, W_out, b_out, W_hh, b_hh, W_ih, fc2_w, Wt_all, b_all, WihT, fc2T);

  gather_h0<<<dim3(MR * 64 / 256), dim3(256), 0, stream>>>(items, emb, h0, h0h, h0l, MR * 64);

  // C1 = h0 @ [W_in|W_out|W_hh] + [b_in|b_out|b_hh]
  gemm_asplit_nt<<<dim3(1280 / 128, MR / 128), dim3(256), 0, stream>>>(
      h0h, h0l, Wt_all, b_all, C1, 1280, 256, 1280);

  msg_kernel<<<dim3(BB), dim3(256), 0, stream>>>(A, C1, acat_h, acat_l);

  // gi = a_cat @ W_ih + b_ih
  gemm_asplit_nt<<<dim3(768 / 128, MR / 128), dim3(256), 0, stream>>>(
      acat_h, acat_l, WihT, b_ih, gi, 768, 512, 768);

  gru_kernel<<<dim3(MR * HH / 256), dim3(256), 0, stream>>>(gi, C1, h0, MR * HH);

  seq_gather<<<dim3(BB), dim3(256), 0, stream>>>(seq_al, mask, h0, h_seqs, hs_h, hs_l, h_tail);

  // q2 = h_seqs @ fc2 + b
  gemm_asplit_nt<<<dim3(256 / 128, (BB * LSEQ) / 128), dim3(256), 0, stream>>>(
      hs_h, hs_l, fc2T, fc2_b, q2, 256, 256, 256);

  // q1 (tiny, fp32)
  gemm_nn_bias<<<dim3(HH / TS, BB / TS), dim3(256), 0, stream>>>(h_tail, fc1_w, fc1_b, q1, BB, HH, HH);

  attn_kernel<<<dim3(BB), dim3(256), 0, stream>>>(q1, q2, fc3_w, h_seqs, mask, seq_emb);

  split_seq<<<dim3(BB * HH / 256), dim3(256), 0, stream>>>(seq_emb, seq_hi, seq_lo, BB * HH);

  scorer_mfma<<<dim3((VOC + 63) / 64, 2), dim3(256), 0, stream>>>(seq_hi, seq_lo, emb, out);
}